// Round 2
// baseline (340.320 us; speedup 1.0000x reference)
//
#include <hip/hip_runtime.h>
#include <math.h>

#define N_NODES 50000
#define E_EDGES 800000
#define F_INDIM 128
#define HID 32
#define C_OUT 16

// ---- CSR build ----------------------------------------------------------
__global__ __launch_bounds__(256) void k_count(const int* __restrict__ ei,
                                               int* __restrict__ deg) {
    int e = blockIdx.x * 256 + threadIdx.x;
    if (e < E_EDGES) atomicAdd(&deg[ei[E_EDGES + e]], 1);
}

// single block, 1024 threads: exclusive scan of deg -> rowptr (+ cursor copy)
__global__ __launch_bounds__(1024) void k_scan(const int* __restrict__ deg,
                                               int* __restrict__ rowptr,
                                               int* __restrict__ cursor) {
    __shared__ int part[1024];
    const int T = 1024;
    const int tid = threadIdx.x;
    const int chunk = (N_NODES + T - 1) / T;
    const int lo = tid * chunk;
    const int hi = (lo + chunk < N_NODES) ? lo + chunk : N_NODES;
    int s = 0;
    for (int i = lo; i < hi; ++i) s += deg[i];
    part[tid] = s;
    __syncthreads();
    for (int d = 1; d < T; d <<= 1) {
        int v = (tid >= d) ? part[tid - d] : 0;
        __syncthreads();
        part[tid] += v;
        __syncthreads();
    }
    int base = (tid > 0) ? part[tid - 1] : 0;
    for (int i = lo; i < hi; ++i) {
        rowptr[i] = base;
        cursor[i] = base;
        base += deg[i];
    }
    if (tid == T - 1) rowptr[N_NODES] = base;
}

__global__ __launch_bounds__(256) void k_fill(const int* __restrict__ ei,
                                              const float* __restrict__ ea,
                                              int* __restrict__ cursor,
                                              int* __restrict__ esrc,
                                              float* __restrict__ ew) {
    int e = blockIdx.x * 256 + threadIdx.x;
    if (e >= E_EDGES) return;
    int p = atomicAdd(&cursor[ei[E_EDGES + e]], 1);
    esrc[p] = ei[e];
    ew[p] = ea[e];
}

// ---- K1: t1 = x @ W_rel1 ; t2b = x @ W_root1 + b1 -----------------------
__global__ __launch_bounds__(256) void k1_dense(
        const float* __restrict__ x,
        const float* __restrict__ Wrel, const float* __restrict__ Wroot,
        const float* __restrict__ b1,
        float* __restrict__ t1, float* __restrict__ t2b) {
    __shared__ float sW1[F_INDIM][HID];
    __shared__ float sW2[F_INDIM][HID];
    __shared__ float sx[8][F_INDIM];
    const int tid = threadIdx.x;
    const int rowBase = blockIdx.x * 8;
    for (int i = tid; i < F_INDIM * HID; i += 256) {
        sW1[i >> 5][i & 31] = Wrel[i];
        sW2[i >> 5][i & 31] = Wroot[i];
    }
    for (int i = tid; i < 8 * F_INDIM; i += 256) {
        int rr = rowBase + (i >> 7);
        sx[i >> 7][i & 127] = (rr < N_NODES) ? x[(size_t)rr * F_INDIM + (i & 127)] : 0.f;
    }
    __syncthreads();
    const int r = rowBase + (tid >> 5);
    const int c = tid & 31;
    if (r >= N_NODES) return;
    float acc1 = 0.f, acc2 = 0.f;
    const int lr = tid >> 5;
#pragma unroll 8
    for (int k = 0; k < F_INDIM; ++k) {
        float xv = sx[lr][k];
        acc1 = fmaf(xv, sW1[k][c], acc1);
        acc2 = fmaf(xv, sW2[k][c], acc2);
    }
    t1[(size_t)r * HID + c] = acc1;
    t2b[(size_t)r * HID + c] = acc2 + b1[c];
}

// ---- Gather layer 1 (fused +t2b, relu) ----------------------------------
// wave per node: 64 lanes = 2 edge-rows x 32 cols
__global__ __launch_bounds__(256) void k_gather1(
        const int* __restrict__ rowptr, const int* __restrict__ esrc,
        const float* __restrict__ ew,
        const float* __restrict__ t1, const float* __restrict__ t2b,
        float* __restrict__ h) {
    const int tid = threadIdx.x;
    const int lane = tid & 63;
    const int node = blockIdx.x * 4 + (tid >> 6);
    if (node >= N_NODES) return;
    const int start = rowptr[node];
    const int end = rowptr[node + 1];
    const int er = lane >> 5;
    const int c = lane & 31;
    float acc = 0.f;
    for (int e = start + er; e < end; e += 2)
        acc = fmaf(ew[e], t1[(size_t)esrc[e] * HID + c], acc);
    acc += __shfl_xor(acc, 32);
    float v = acc + t2b[(size_t)node * HID + c];
    v = v > 0.f ? v : 0.f;
    if (er == 0) h[(size_t)node * HID + c] = v;
}

// ---- K3: u1 = h@W_rel2 ; u2b = h@W_root2 + b2 ---------------------------
__global__ __launch_bounds__(256) void k3_layer2(
        const float* __restrict__ h,
        const float* __restrict__ Wrel2, const float* __restrict__ Wroot2,
        const float* __restrict__ b2,
        float* __restrict__ u1, float* __restrict__ u2b) {
    __shared__ float sW1[HID][C_OUT];
    __shared__ float sW2[HID][C_OUT];
    __shared__ float sh[16][HID + 1];
    const int tid = threadIdx.x;
    const int rowBase = blockIdx.x * 16;
    for (int i = tid; i < HID * C_OUT; i += 256) {
        sW1[i >> 4][i & 15] = Wrel2[i];
        sW2[i >> 4][i & 15] = Wroot2[i];
    }
    for (int i = tid; i < 16 * HID; i += 256) {
        int rr = rowBase + (i >> 5);
        int cc = i & 31;
        sh[i >> 5][cc] = (rr < N_NODES) ? h[(size_t)rr * HID + cc] : 0.f;
    }
    __syncthreads();
    const int r = rowBase + (tid >> 4);
    const int c = tid & 15;
    if (r >= N_NODES) return;
    const int lr = tid >> 4;
    float a1 = 0.f, a2 = 0.f;
#pragma unroll
    for (int k = 0; k < HID; ++k) {
        float hv = sh[lr][k];
        a1 = fmaf(hv, sW1[k][c], a1);
        a2 = fmaf(hv, sW2[k][c], a2);
    }
    u1[(size_t)r * C_OUT + c] = a1;
    u2b[(size_t)r * C_OUT + c] = a2 + b2[c];
}

// ---- Gather layer 2 (fused +u2b, log_softmax) ---------------------------
// wave per node: 64 lanes = 4 edge-rows x 16 cols
__global__ __launch_bounds__(256) void k_gather2(
        const int* __restrict__ rowptr, const int* __restrict__ esrc,
        const float* __restrict__ ew,
        const float* __restrict__ u1, const float* __restrict__ u2b,
        float* __restrict__ out) {
    const int tid = threadIdx.x;
    const int lane = tid & 63;
    const int node = blockIdx.x * 4 + (tid >> 6);
    if (node >= N_NODES) return;
    const int start = rowptr[node];
    const int end = rowptr[node + 1];
    const int er = lane >> 4;
    const int c = lane & 15;
    float acc = 0.f;
    for (int e = start + er; e < end; e += 4)
        acc = fmaf(ew[e], u1[(size_t)esrc[e] * C_OUT + c], acc);
    acc += __shfl_xor(acc, 16);
    acc += __shfl_xor(acc, 32);
    float v = acc + u2b[(size_t)node * C_OUT + c];
    float mx = v;
#pragma unroll
    for (int d = 1; d < 16; d <<= 1) mx = fmaxf(mx, __shfl_xor(mx, d));
    float ex = expf(v - mx);
    float s = ex;
#pragma unroll
    for (int d = 1; d < 16; d <<= 1) s += __shfl_xor(s, d);
    float o = v - mx - logf(s);
    if (er == 0) out[(size_t)node * C_OUT + c] = o;
}

extern "C" void kernel_launch(void* const* d_in, const int* in_sizes, int n_in,
                              void* d_out, int out_size, void* d_ws, size_t ws_size,
                              hipStream_t stream) {
    const float* x      = (const float*)d_in[0];
    const int*   ei     = (const int*)d_in[1];
    const float* ea     = (const float*)d_in[2];
    const float* Wrel1  = (const float*)d_in[3];
    const float* Wroot1 = (const float*)d_in[4];
    const float* b1     = (const float*)d_in[5];
    const float* Wrel2  = (const float*)d_in[6];
    const float* Wroot2 = (const float*)d_in[7];
    const float* b2     = (const float*)d_in[8];
    float* out = (float*)d_out;

    float* ws = (float*)d_ws;
    // t1 [N*32] is dead after k_gather1; u1/u2b reuse its slot.
    float* t1   = ws;                                  // N*32
    float* u1   = ws;                                  // N*16 (reuse)
    float* u2b  = ws + (size_t)N_NODES * 16;           // N*16 (reuse)
    float* t2b  = ws + (size_t)N_NODES * 32;           // N*32
    float* h    = ws + (size_t)N_NODES * 64;           // N*32
    float* ew   = ws + (size_t)N_NODES * 96;           // E
    int*   esrc = (int*)(ws + (size_t)N_NODES * 96 + E_EDGES);      // E
    int*   deg  = (int*)(ws + (size_t)N_NODES * 96 + 2 * E_EDGES);  // N
    int*   rowptr = deg + N_NODES;                     // N+1
    int*   cursor = rowptr + N_NODES + 1;              // N
    // total: N*96 + 2E + 3N+1 floats = ~26.2 MB

    hipMemsetAsync(deg, 0, (size_t)N_NODES * sizeof(int), stream);
    k_count<<<(E_EDGES + 255) / 256, 256, 0, stream>>>(ei, deg);
    k_scan<<<1, 1024, 0, stream>>>(deg, rowptr, cursor);
    k_fill<<<(E_EDGES + 255) / 256, 256, 0, stream>>>(ei, ea, cursor, esrc, ew);

    k1_dense<<<(N_NODES + 7) / 8, 256, 0, stream>>>(x, Wrel1, Wroot1, b1, t1, t2b);
    k_gather1<<<(N_NODES + 3) / 4, 256, 0, stream>>>(rowptr, esrc, ew, t1, t2b, h);
    k3_layer2<<<(N_NODES + 15) / 16, 256, 0, stream>>>(h, Wrel2, Wroot2, b2, u1, u2b);
    k_gather2<<<(N_NODES + 3) / 4, 256, 0, stream>>>(rowptr, esrc, ew, u1, u2b, out);
}

// Round 3
// 219.087 us; speedup vs baseline: 1.5534x; 1.5534x over previous
//
#include <hip/hip_runtime.h>
#include <math.h>

#define N_NODES 50000
#define E_EDGES 800000
#define F_INDIM 128
#define HID 32
#define C_OUT 16
#define SCAN_BLK 49   // ceil(50000/1024)

// ---- CSR build ----------------------------------------------------------
__global__ __launch_bounds__(256) void k_count(const int* __restrict__ ei,
                                               int* __restrict__ deg) {
    int e = blockIdx.x * 256 + threadIdx.x;
    if (e < E_EDGES) atomicAdd(&deg[ei[E_EDGES + e]], 1);
}

// stage 1: per-block (1024 elems) sum -> blocksum[49]
__global__ __launch_bounds__(256) void k_scan1(const int* __restrict__ deg,
                                               int* __restrict__ blocksum) {
    const int tid = threadIdx.x;
    const int base = blockIdx.x * 1024 + tid * 4;
    int4 v = make_int4(0, 0, 0, 0);
    if (base < N_NODES) v = *(const int4*)(deg + base);   // N%4==0 -> full vec
    int s = v.x + v.y + v.z + v.w;
#pragma unroll
    for (int d = 1; d < 64; d <<= 1) s += __shfl_xor(s, d);
    __shared__ int wsum[4];
    if ((tid & 63) == 0) wsum[tid >> 6] = s;
    __syncthreads();
    if (tid == 0) blocksum[blockIdx.x] = wsum[0] + wsum[1] + wsum[2] + wsum[3];
}

// stage 2: one wave scans the 49 block sums -> exclusive bases (in place)
__global__ __launch_bounds__(64) void k_scan2(int* __restrict__ blocksum,
                                              int* __restrict__ rowptr) {
    const int lane = threadIdx.x;
    int orig = (lane < SCAN_BLK) ? blocksum[lane] : 0;
    int v = orig;
#pragma unroll
    for (int d = 1; d < 64; d <<= 1) {
        int t = __shfl_up(v, d);
        if (lane >= d) v += t;
    }
    if (lane < SCAN_BLK) blocksum[lane] = v - orig;   // exclusive base
    if (lane == 0) rowptr[N_NODES] = E_EDGES;         // total degree is E
}

// stage 3: rescan chunk, add base, write rowptr + cursor (int4 stores)
__global__ __launch_bounds__(256) void k_scan3(const int* __restrict__ deg,
                                               const int* __restrict__ blocksum,
                                               int* __restrict__ rowptr,
                                               int* __restrict__ cursor) {
    const int tid = threadIdx.x;
    const int lane = tid & 63;
    const int base = blockIdx.x * 1024 + tid * 4;
    int4 v = make_int4(0, 0, 0, 0);
    if (base < N_NODES) v = *(const int4*)(deg + base);
    const int s = v.x + v.y + v.z + v.w;
    int inc = s;
#pragma unroll
    for (int d = 1; d < 64; d <<= 1) {
        int t = __shfl_up(inc, d);
        if (lane >= d) inc += t;
    }
    __shared__ int wsum[4];
    if (lane == 63) wsum[tid >> 6] = inc;
    __syncthreads();
    const int mw = tid >> 6;
    int wb = 0;
    if (mw > 0) wb += wsum[0];
    if (mw > 1) wb += wsum[1];
    if (mw > 2) wb += wsum[2];
    if (base < N_NODES) {
        int ex = blocksum[blockIdx.x] + wb + inc - s;  // exclusive prefix
        int4 rp;
        rp.x = ex;
        rp.y = ex + v.x;
        rp.z = ex + v.x + v.y;
        rp.w = ex + v.x + v.y + v.z;
        *(int4*)(rowptr + base) = rp;
        *(int4*)(cursor + base) = rp;
    }
}

__global__ __launch_bounds__(256) void k_fill(const int* __restrict__ ei,
                                              const float* __restrict__ ea,
                                              int* __restrict__ cursor,
                                              int* __restrict__ esrc,
                                              float* __restrict__ ew) {
    int e = blockIdx.x * 256 + threadIdx.x;
    if (e >= E_EDGES) return;
    int p = atomicAdd(&cursor[ei[E_EDGES + e]], 1);
    esrc[p] = ei[e];
    ew[p] = ea[e];
}

// ---- K1: t1 = x @ W_rel1 ; t2b = x @ W_root1 + b1 -----------------------
__global__ __launch_bounds__(256) void k1_dense(
        const float* __restrict__ x,
        const float* __restrict__ Wrel, const float* __restrict__ Wroot,
        const float* __restrict__ b1,
        float* __restrict__ t1, float* __restrict__ t2b) {
    __shared__ float sW1[F_INDIM][HID];
    __shared__ float sW2[F_INDIM][HID];
    __shared__ float sx[8][F_INDIM];
    const int tid = threadIdx.x;
    const int rowBase = blockIdx.x * 8;
    for (int i = tid; i < F_INDIM * HID; i += 256) {
        sW1[i >> 5][i & 31] = Wrel[i];
        sW2[i >> 5][i & 31] = Wroot[i];
    }
    for (int i = tid; i < 8 * F_INDIM; i += 256) {
        int rr = rowBase + (i >> 7);
        sx[i >> 7][i & 127] = (rr < N_NODES) ? x[(size_t)rr * F_INDIM + (i & 127)] : 0.f;
    }
    __syncthreads();
    const int r = rowBase + (tid >> 5);
    const int c = tid & 31;
    if (r >= N_NODES) return;
    float acc1 = 0.f, acc2 = 0.f;
    const int lr = tid >> 5;
#pragma unroll 8
    for (int k = 0; k < F_INDIM; ++k) {
        float xv = sx[lr][k];
        acc1 = fmaf(xv, sW1[k][c], acc1);
        acc2 = fmaf(xv, sW2[k][c], acc2);
    }
    t1[(size_t)r * HID + c] = acc1;
    t2b[(size_t)r * HID + c] = acc2 + b1[c];
}

// ---- Gather layer 1 (fused +t2b, relu) ----------------------------------
// wave per node: 64 lanes = 2 edge-rows x 32 cols; 2 accumulators for MLP
__global__ __launch_bounds__(256) void k_gather1(
        const int* __restrict__ rowptr, const int* __restrict__ esrc,
        const float* __restrict__ ew,
        const float* __restrict__ t1, const float* __restrict__ t2b,
        float* __restrict__ h) {
    const int tid = threadIdx.x;
    const int lane = tid & 63;
    const int node = blockIdx.x * 4 + (tid >> 6);
    if (node >= N_NODES) return;
    const int start = rowptr[node];
    const int end = rowptr[node + 1];
    const int er = lane >> 5;
    const int c = lane & 31;
    float a0 = 0.f, a1 = 0.f;
    int e = start + er;
    for (; e + 2 < end; e += 4) {
        a0 = fmaf(ew[e],     t1[(size_t)esrc[e]     * HID + c], a0);
        a1 = fmaf(ew[e + 2], t1[(size_t)esrc[e + 2] * HID + c], a1);
    }
    if (e < end)
        a0 = fmaf(ew[e], t1[(size_t)esrc[e] * HID + c], a0);
    float acc = a0 + a1;
    acc += __shfl_xor(acc, 32);
    float v = acc + t2b[(size_t)node * HID + c];
    v = v > 0.f ? v : 0.f;
    if (er == 0) h[(size_t)node * HID + c] = v;
}

// ---- K3: u1 = h@W_rel2 ; u2b = h@W_root2 + b2 ---------------------------
__global__ __launch_bounds__(256) void k3_layer2(
        const float* __restrict__ h,
        const float* __restrict__ Wrel2, const float* __restrict__ Wroot2,
        const float* __restrict__ b2,
        float* __restrict__ u1, float* __restrict__ u2b) {
    __shared__ float sW1[HID][C_OUT];
    __shared__ float sW2[HID][C_OUT];
    __shared__ float sh[16][HID + 1];
    const int tid = threadIdx.x;
    const int rowBase = blockIdx.x * 16;
    for (int i = tid; i < HID * C_OUT; i += 256) {
        sW1[i >> 4][i & 15] = Wrel2[i];
        sW2[i >> 4][i & 15] = Wroot2[i];
    }
    for (int i = tid; i < 16 * HID; i += 256) {
        int rr = rowBase + (i >> 5);
        int cc = i & 31;
        sh[i >> 5][cc] = (rr < N_NODES) ? h[(size_t)rr * HID + cc] : 0.f;
    }
    __syncthreads();
    const int r = rowBase + (tid >> 4);
    const int c = tid & 15;
    if (r >= N_NODES) return;
    const int lr = tid >> 4;
    float a1 = 0.f, a2 = 0.f;
#pragma unroll
    for (int k = 0; k < HID; ++k) {
        float hv = sh[lr][k];
        a1 = fmaf(hv, sW1[k][c], a1);
        a2 = fmaf(hv, sW2[k][c], a2);
    }
    u1[(size_t)r * C_OUT + c] = a1;
    u2b[(size_t)r * C_OUT + c] = a2 + b2[c];
}

// ---- Gather layer 2 (fused +u2b, log_softmax) ---------------------------
// wave per node: 64 lanes = 4 edge-rows x 16 cols; 2 accumulators
__global__ __launch_bounds__(256) void k_gather2(
        const int* __restrict__ rowptr, const int* __restrict__ esrc,
        const float* __restrict__ ew,
        const float* __restrict__ u1, const float* __restrict__ u2b,
        float* __restrict__ out) {
    const int tid = threadIdx.x;
    const int lane = tid & 63;
    const int node = blockIdx.x * 4 + (tid >> 6);
    if (node >= N_NODES) return;
    const int start = rowptr[node];
    const int end = rowptr[node + 1];
    const int er = lane >> 4;
    const int c = lane & 15;
    float a0 = 0.f, a1 = 0.f;
    int e = start + er;
    for (; e + 4 < end; e += 8) {
        a0 = fmaf(ew[e],     u1[(size_t)esrc[e]     * C_OUT + c], a0);
        a1 = fmaf(ew[e + 4], u1[(size_t)esrc[e + 4] * C_OUT + c], a1);
    }
    if (e < end)
        a0 = fmaf(ew[e], u1[(size_t)esrc[e] * C_OUT + c], a0);
    float acc = a0 + a1;
    acc += __shfl_xor(acc, 16);
    acc += __shfl_xor(acc, 32);
    float v = acc + u2b[(size_t)node * C_OUT + c];
    float mx = v;
#pragma unroll
    for (int d = 1; d < 16; d <<= 1) mx = fmaxf(mx, __shfl_xor(mx, d));
    float ex = expf(v - mx);
    float s = ex;
#pragma unroll
    for (int d = 1; d < 16; d <<= 1) s += __shfl_xor(s, d);
    float o = v - mx - logf(s);
    if (er == 0) out[(size_t)node * C_OUT + c] = o;
}

extern "C" void kernel_launch(void* const* d_in, const int* in_sizes, int n_in,
                              void* d_out, int out_size, void* d_ws, size_t ws_size,
                              hipStream_t stream) {
    const float* x      = (const float*)d_in[0];
    const int*   ei     = (const int*)d_in[1];
    const float* ea     = (const float*)d_in[2];
    const float* Wrel1  = (const float*)d_in[3];
    const float* Wroot1 = (const float*)d_in[4];
    const float* b1     = (const float*)d_in[5];
    const float* Wrel2  = (const float*)d_in[6];
    const float* Wroot2 = (const float*)d_in[7];
    const float* b2     = (const float*)d_in[8];
    float* out = (float*)d_out;

    float* ws = (float*)d_ws;
    // t1 [N*32] is dead after k_gather1; u1/u2b reuse its slot.
    float* t1   = ws;                                  // N*32
    float* u1   = ws;                                  // N*16 (reuse)
    float* u2b  = ws + (size_t)N_NODES * 16;           // N*16 (reuse)
    float* t2b  = ws + (size_t)N_NODES * 32;           // N*32
    float* h    = ws + (size_t)N_NODES * 64;           // N*32
    float* ew   = ws + (size_t)N_NODES * 96;           // E
    int*   esrc = (int*)(ws + (size_t)N_NODES * 96 + E_EDGES);      // E
    int*   deg  = (int*)(ws + (size_t)N_NODES * 96 + 2 * E_EDGES);  // N
    int*   rowptr = deg + N_NODES;                     // N+1
    int*   cursor = rowptr + N_NODES + 1;              // N
    int*   blocksum = cursor + N_NODES;                // 64
    // total: ~26.2 MB

    hipMemsetAsync(deg, 0, (size_t)N_NODES * sizeof(int), stream);
    k_count<<<(E_EDGES + 255) / 256, 256, 0, stream>>>(ei, deg);
    k_scan1<<<SCAN_BLK, 256, 0, stream>>>(deg, blocksum);
    k_scan2<<<1, 64, 0, stream>>>(blocksum, rowptr);
    k_scan3<<<SCAN_BLK, 256, 0, stream>>>(deg, blocksum, rowptr, cursor);
    k_fill<<<(E_EDGES + 255) / 256, 256, 0, stream>>>(ei, ea, cursor, esrc, ew);

    k1_dense<<<(N_NODES + 7) / 8, 256, 0, stream>>>(x, Wrel1, Wroot1, b1, t1, t2b);
    k_gather1<<<(N_NODES + 3) / 4, 256, 0, stream>>>(rowptr, esrc, ew, t1, t2b, h);
    k3_layer2<<<(N_NODES + 15) / 16, 256, 0, stream>>>(h, Wrel2, Wroot2, b2, u1, u2b);
    k_gather2<<<(N_NODES + 3) / 4, 256, 0, stream>>>(rowptr, esrc, ew, u1, u2b, out);
}